// Round 7
// baseline (147.015 us; speedup 1.0000x reference)
//
#include <hip/hip_runtime.h>

#pragma clang fp contract(off)

#define NP 410881  // 641*641

// ---------------------------------------------------------------------------
// Single fused kernel (round 7).
//  - Each 512-thread block covers a 32x16 output region (2 px/thread,
//    channels half-split across thread pairs; halves merge via LDS).
//  - Slot tables (argmax/conf/cumsum over probs 128x134) computed per block
//    from the L2-hot 68KB probs buffer: no serial pre-kernel, no gap.
//  - XCD-band swizzle: grid padded to 864 = 8*108; bid=(8*pos+xcd) maps to
//    lin=xcd*108+pos so each XCD owns a contiguous band (~1.7MB < 4MB L2).
//  - Explicit register prefetch of the next 4-channel texel group.
// ---------------------------------------------------------------------------
__global__ __launch_bounds__(512) void fused_kernel(
    const float* __restrict__ logits, const float* __restrict__ probs,
    float* __restrict__ out) {
#pragma clang fp contract(off)
  __shared__ float s_rv[128];
  __shared__ int s_ra[128];
  __shared__ float s_cls[128];
  __shared__ int s_didx[128];
  __shared__ unsigned long long s_mask[2];
  __shared__ int s_ndet;
  // per-pixel cross-half merge buffers (pixel A = x0, pixel B = x0+1)
  __shared__ float sAm[256], sAT[256], sArm[256];
  __shared__ float sBm[256], sBT[256], sBrm[256];
  __shared__ int sAa[256], sBa[256];

  // ---- XCD-band swizzle (bijection on [0,864)) ----
  int bid = blockIdx.x;
  int lin = (bid & 7) * 108 + (bid >> 3);
  if (lin >= 861) return;  // whole block exits before any barrier
  int by = lin / 21, bx = lin - by * 21;

  int t = threadIdx.x;

  // ---- slot tables, computed per block ----
  {
    int r = t >> 2, q = t & 3;  // 4 threads per row; contiguous col chunks
    int j0 = q * 34;
    int j1 = min(j0 + 34, 133);
    const float* row = probs + r * 134;
    float bv = -1.0f;
    int bi = j0;
    for (int j = j0; j < j1; ++j) {
      float p = row[j];
      if (p > bv) { bv = p; bi = j; }  // strict > keeps first index
    }
#pragma unroll
    for (int off = 1; off <= 2; off <<= 1) {  // reduce the 4 chunks (adjacent lanes)
      float ov = __shfl_xor(bv, off);
      int oi = __shfl_xor(bi, off);
      if (ov > bv || (ov == bv && oi < bi)) { bv = ov; bi = oi; }
    }
    if (q == 0) { s_rv[r] = bv; s_ra[r] = bi; }
  }
  __syncthreads();
  {
    int wv = t >> 6, lane = t & 63;
    bool flag = false;
    if (t < 128) {  // waves 0,1 fully active
      flag = (s_rv[t] >= 0.7f);
      unsigned long long b = __ballot(flag);
      if (lane == 0) s_mask[wv] = b;
    }
    __syncthreads();
    if (t < 128) {
      unsigned long long b = s_mask[wv];
      int incl = __popcll(b & ((1ull << lane) - 1)) + (flag ? 1 : 0) +
                 ((t >= 64) ? __popcll(s_mask[0]) : 0);
      s_didx[t] = incl - 1;  // cumsum(det)-1
      s_cls[t] = (float)s_ra[t];
      if (t == 127) s_ndet = incl;
    }
  }
  __syncthreads();

  // ---- pixel mapping: 2 px/thread (one cell x-strip), channel half-split ----
  int p = t & 255, half = t >> 8;
  int sx = p & 15, sy = p >> 4;
  int x0 = (bx << 5) + (sx << 1);  // pixels x0, x0+1
  int y = (by << 4) + sy;
  int x0c = min(x0, 640), x1c = min(x0 + 1, 640), yc = min(y, 640);
  bool vA = (x0 <= 640) && (y <= 640);
  bool vB = (x0 + 1 <= 640) && (y <= 640);

  int ndet = s_ndet;  // uniform
  if (ndet == 0) {    // reference zeroes everything when nothing detected
    if (half == 0 && y <= 640) {
      if (vA) {
        int i = y * 641 + x0;
        out[i] = 1.0f; out[NP + i] = 0.f; out[2 * NP + i] = 0.f; out[3 * NP + i] = 0.f;
      }
      if (vB) {
        int i = y * 641 + x0 + 1;
        out[i] = 1.0f; out[NP + i] = 0.f; out[2 * NP + i] = 0.f; out[3 * NP + i] = 0.f;
      }
    }
    return;
  }

  // texel coords + weights (scale exactly 1/4; both px share one cell)
  int tx0 = x0c >> 2, ty0 = yc >> 2;
  int tx1 = min(tx0 + 1, 160), ty1 = min(ty0 + 1, 160);
  float wx0 = 0.25f * (float)(x0c & 3), iwx0 = 1.0f - wx0;
  float wx1 = 0.25f * (float)(x1c & 3), iwx1 = 1.0f - wx1;
  float wy = 0.25f * (float)(yc & 3), iwy = 1.0f - wy;

  int co = half << 6;  // this half's channel offset
  const float* P00 = logits + ((ty0 * 161 + tx0) << 7) + co;
  const float* P01 = logits + ((ty0 * 161 + tx1) << 7) + co;
  const float* P10 = logits + ((ty1 * 161 + tx0) << 7) + co;
  const float* P11 = logits + ((ty1 * 161 + tx1) << 7) + co;

  float mA = -INFINITY, mB = -INFINITY;  // this half's masked max
  int aA = 0, aB = 0;                    // masked argmax (global channel id)
  float TA = 0.f, TB = 0.f;              // sum exp(v) over detected
  float rmA = -INFINITY, rmB = -INFINITY;

  if (ndet == 128) {  // fast path: masked == resized
    float msA[2], msB[2], TsA[2], TsB[2];
    int asA[2], asB[2];
#pragma unroll
    for (int j = 0; j < 2; ++j) {
      msA[j] = -INFINITY; msB[j] = -INFINITY;
      TsA[j] = 0.f; TsB[j] = 0.f; asA[j] = 0; asB[j] = 0;
    }
// one channel; y-interp (r0,r1) shared by the px pair; reference op order
#define CH(A00, A01, A10, A11, CIDX, J)                                        \
  {                                                                            \
    float r0 = (A00) * iwy + (A10) * wy;                                       \
    float r1 = (A01) * iwy + (A11) * wy;                                       \
    float vva = r0 * iwx0 + r1 * wx0;                                          \
    float vvb = r0 * iwx1 + r1 * wx1;                                          \
    bool ga = vva > msA[J]; msA[J] = ga ? vva : msA[J]; asA[J] = ga ? (CIDX) : asA[J]; \
    bool gb = vvb > msB[J]; msB[J] = gb ? vvb : msB[J]; asB[J] = gb ? (CIDX) : asB[J]; \
    TsA[J] += __expf(vva);                                                     \
    TsB[J] += __expf(vvb);                                                     \
  }
    float4 n00 = *(const float4*)(P00);
    float4 n01 = *(const float4*)(P01);
    float4 n10 = *(const float4*)(P10);
    float4 n11 = *(const float4*)(P11);
#pragma unroll 4
    for (int c = 0; c < 64; c += 4) {
      float4 q00 = n00, q01 = n01, q10 = n10, q11 = n11;
      if (c + 4 < 64) {  // prefetch next 4-channel group
        n00 = *(const float4*)(P00 + c + 4);
        n01 = *(const float4*)(P01 + c + 4);
        n10 = *(const float4*)(P10 + c + 4);
        n11 = *(const float4*)(P11 + c + 4);
      }
      CH(q00.x, q01.x, q10.x, q11.x, co + c + 0, 0);
      CH(q00.y, q01.y, q10.y, q11.y, co + c + 1, 1);
      CH(q00.z, q01.z, q10.z, q11.z, co + c + 2, 0);
      CH(q00.w, q01.w, q10.w, q11.w, co + c + 3, 1);
    }
#undef CH
    // exact merge: global max; on value tie, smallest channel index wins
    mA = msA[0]; aA = asA[0]; mB = msB[0]; aB = asB[0];
    if (msA[1] > mA || (msA[1] == mA && asA[1] < aA)) { mA = msA[1]; aA = asA[1]; }
    if (msB[1] > mB || (msB[1] == mB && asB[1] < aB)) { mB = msB[1]; aB = asB[1]; }
    TA = TsA[0] + TsA[1];
    TB = TsB[0] + TsB[1];
    rmA = mA; rmB = mB;
  } else {  // general path (not taken for this input; correctness only)
    unsigned long long msk = s_mask[half];
#pragma unroll 4
    for (int c = 0; c < 64; ++c) {
      float a00 = P00[c], a01 = P01[c];
      float a10 = P10[c], a11 = P11[c];
      float r0 = a00 * iwy + a10 * wy;
      float r1 = a01 * iwy + a11 * wy;
      float vva = r0 * iwx0 + r1 * wx0;
      float vvb = r0 * iwx1 + r1 * wx1;
      rmA = fmaxf(rmA, vva);
      rmB = fmaxf(rmB, vvb);
      if ((msk >> c) & 1) {  // wave-uniform branch
        bool ga = vva > mA; mA = ga ? vva : mA; aA = ga ? (co + c) : aA;
        bool gb = vvb > mB; mB = gb ? vvb : mB; aB = gb ? (co + c) : aB;
        TA += __expf(vva);
        TB += __expf(vvb);
      }
    }
  }

  // ---- cross-half merge via LDS ----
  if (half == 1) {
    sAm[p] = mA; sAa[p] = aA; sAT[p] = TA; sArm[p] = rmA;
    sBm[p] = mB; sBa[p] = aB; sBT[p] = TB; sBrm[p] = rmB;
  }
  __syncthreads();
  if (half == 0) {
    // half0 channels (0..63) < half1 (64..127): prefer half0 on value tie
    float hm = sAm[p]; int ha = sAa[p];
    if (hm > mA) { mA = hm; aA = ha; }
    TA += sAT[p];
    rmA = fmaxf(rmA, sArm[p]);
    hm = sBm[p]; ha = sBa[p];
    if (hm > mB) { mB = hm; aB = ha; }
    TB += sBT[p];
    rmB = fmaxf(rmB, sBrm[p]);
    bool dpA = (rmA == mA), dpB = (rmB == mB);

    // conf > 0.4  <=>  exp(m) > 0.4*T  (T > 0, |v| bounded)
    float cgA = ((__expf(mA) > 0.4f * TA) && dpA) ? 1.0f : 0.0f;
    float cgB = ((__expf(mB) > 0.4f * TB) && dpB) ? 1.0f : 0.0f;
    float semA = s_cls[aA], semB = s_cls[aB];
    float midA = (float)(s_didx[aA] + 1), midB = (float)(s_didx[aB] + 1);
    float thA = (semA < 80.f) ? cgA : 0.f, stA = cgA - thA;
    float thB = (semB < 80.f) ? cgB : 0.f, stB = cgB - thB;

    if (vA) {
      int i = y * 641 + x0;
      out[i] = midA; out[NP + i] = semA; out[2 * NP + i] = thA; out[3 * NP + i] = stA;
    }
    if (vB) {
      int i = y * 641 + x0 + 1;
      out[i] = midB; out[NP + i] = semB; out[2 * NP + i] = thB; out[3 * NP + i] = stB;
    }
  }
}

extern "C" void kernel_launch(void* const* d_in, const int* in_sizes, int n_in,
                              void* d_out, int out_size, void* d_ws,
                              size_t ws_size, hipStream_t stream) {
  const float* logits = (const float*)d_in[0];  // (161,161,128) f32
  const float* probs = (const float*)d_in[1];   // (128,134) f32
  float* out = (float*)d_out;

  // 861 active tiles (21 x 41 regions of 32x16), padded to 864 = 8*108 for
  // the XCD-band swizzle bijection.
  fused_kernel<<<864, 512, 0, stream>>>(logits, probs, out);
}